// Round 20
// baseline (174.054 us; speedup 1.0000x reference)
//
#include <hip/hip_runtime.h>
#include <hip/hip_bf16.h>
#include <cstdint>
#include <cstddef>

typedef __attribute__((ext_vector_type(8))) short bf16x8;
typedef __attribute__((ext_vector_type(4))) float f32x4;
typedef __attribute__((ext_vector_type(16))) float f32x16;

#define AS1 __attribute__((address_space(1)))
#define AS3 __attribute__((address_space(3)))

__device__ __forceinline__ void gload_lds16(const void* g, void* l) {
  __builtin_amdgcn_global_load_lds((const AS1 void*)g, (AS3 void*)l, 16, 0, 0);
}

__device__ __forceinline__ unsigned short f2bf(float x) {
  __hip_bfloat16 h = __float2bfloat16(x);
  return __builtin_bit_cast(unsigned short, h);
}
__device__ __forceinline__ float bf2f(unsigned short u) {
  return __builtin_bit_cast(float, (unsigned int)u << 16);
}
__device__ __forceinline__ unsigned cvtpk(float a, float b) {
  unsigned r;
  asm("v_cvt_pk_bf16_f32 %0, %1, %2" : "=v"(r) : "v"(a), "v"(b));
  return r;
}
// v_permlane32_swap_b32 vdst, vsrc: vdst[lanes 32..63] <-> vsrc[lanes 0..31]
__device__ __forceinline__ void pswap(unsigned& x, unsigned& y) {
  asm volatile("v_permlane32_swap_b32 %0, %1" : "+v"(x), "+v"(y));
}

// ============ 1. fused: f32->bf16 converts + RoPE tables ============
__global__ __launch_bounds__(256) void k_cvt3(const float* __restrict__ a, unsigned short* __restrict__ ao, int na4,
                                              const float* __restrict__ b, unsigned short* __restrict__ bo, int nb4,
                                              const float* __restrict__ c, unsigned short* __restrict__ co, int nc4,
                                              float* __restrict__ cosT, float* __restrict__ sinT,
                                              const int* __restrict__ hdim, const int* __restrict__ wdim) {
  const int stride = gridDim.x * 256;
  for (int i = blockIdx.x * 256 + threadIdx.x; i < na4; i += stride) {
    float4 v = reinterpret_cast<const float4*>(a)[i];
    ushort4 o; o.x = f2bf(v.x); o.y = f2bf(v.y); o.z = f2bf(v.z); o.w = f2bf(v.w);
    reinterpret_cast<ushort4*>(ao)[i] = o;
  }
  for (int i = blockIdx.x * 256 + threadIdx.x; i < nb4; i += stride) {
    float4 v = reinterpret_cast<const float4*>(b)[i];
    ushort4 o; o.x = f2bf(v.x); o.y = f2bf(v.y); o.z = f2bf(v.z); o.w = f2bf(v.w);
    reinterpret_cast<ushort4*>(bo)[i] = o;
  }
  for (int i = blockIdx.x * 256 + threadIdx.x; i < nc4; i += stride) {
    float4 v = reinterpret_cast<const float4*>(c)[i];
    ushort4 o; o.x = f2bf(v.x); o.y = f2bf(v.y); o.z = f2bf(v.z); o.w = f2bf(v.w);
    reinterpret_cast<ushort4*>(co)[i] = o;
  }
  const int H = *hdim, W = *wdim;
  for (int idx = blockIdx.x * 256 + threadIdx.x; idx < 2048 * 64; idx += stride) {
    const int n = idx >> 6, j = idx & 63;
    const int w = n % W;
    const int rem = n / W;
    const int h = rem % H;
    const int t = rem / H;
    float pos, i2, d;
    if (j < 22)      { pos = (float)t; i2 = (float)(2 * j);        d = 44.f; }
    else if (j < 43) { pos = (float)h; i2 = (float)(2 * (j - 22)); d = 42.f; }
    else             { pos = (float)w; i2 = (float)(2 * (j - 43)); d = 42.f; }
    const float ang = pos * powf(10000.0f, -i2 / d);
    cosT[idx] = cosf(ang);
    sinT[idx] = sinf(ang);
  }
}

// ============ 3a. QKV GEMM: 256x256 8-phase template (4 phases/K-tile, BK=64).
// 512 thr (8 waves 2Mx4N), dbuf-2 x {A0,A1,B0,B1} 16KB slots = 128KB LDS.
// Quadrant order (mh0,n0),(mh1,n1),(mh0,n1),(mh1,n0); ph3 stages A(j+2),
// ph4 stages B(j+2) + vmcnt(8) (confirms j+1, never drains). bf16 out.
__global__ __launch_bounds__(512, 2) void k_gemmQKV8(const unsigned short* __restrict__ A,
                                                     const unsigned short* __restrict__ B,
                                                     const float* __restrict__ bias,
                                                     unsigned short* __restrict__ C,
                                                     int M, int N, int K) {
  __shared__ __align__(16) char lds[131072];
  const int tid = threadIdx.x;
  const int lane = tid & 63;
  const int wid = tid >> 6;
  const int wr = wid >> 2, wc = wid & 3;      // 2M x 4N waves

  const int xcd = blockIdx.x & 7;
  const int t0 = blockIdx.x >> 3;             // 0..23 per XCD
  const int bx = xcd * 3 + t0 % 3;            // 3 col-tiles per XCD (768 cols, 3MB B)
  const int by = t0 / 3;                      // 0..7
  const int row0 = by * 256, col0 = bx * 256;
  const int NT = K >> 6;                      // 32 K-tiles of 64

  // One slot = 256 rows x 32 k = 16KB, row-pair-packed XOR layout (proven R4+).
  auto stage_slot = [&](const unsigned short* src, int grow0, int kcol0, char* slot) {
#pragma unroll
    for (int r = 0; r < 2; ++r) {
      const int off = r * 8192 + tid * 16;
      const int pair = off >> 7;
      const int un = (off & 127) ^ ((pair & 7) << 4);
      const int grow = pair * 2 + (un >> 6);
      gload_lds16(src + (size_t)(grow0 + grow) * K + kcol0 + ((un & 63) >> 1),
                  slot + r * 8192 + wid * 1024);
    }
  };
  auto frag = [&](const char* slot, int r, int kb) -> bf16x8 {
    return *reinterpret_cast<const bf16x8*>(
        slot + (r >> 1) * 128 + ((((r & 1) << 6) + kb) ^ (((r >> 1) & 7) << 4)));
  };

  f32x4 acc[8][4];
#pragma unroll
  for (int i = 0; i < 8; ++i)
#pragma unroll
    for (int j = 0; j < 4; ++j) acc[i][j] = (f32x4){0.f, 0.f, 0.f, 0.f};

  // buf b @ b*65536: A0 @+0, A1 @+16384, B0 @+32768, B1 @+49152
  // Prologue: tiles 0,1 fully staged (16 loads); vmcnt(8) confirms tile 0.
#pragma unroll
  for (int p = 0; p < 2; ++p) {
    char* buf = lds + p * 65536;
    stage_slot(A, row0, p * 64,      buf);
    stage_slot(A, row0, p * 64 + 32, buf + 16384);
    stage_slot(B, col0, p * 64,      buf + 32768);
    stage_slot(B, col0, p * 64 + 32, buf + 49152);
  }
  asm volatile("s_waitcnt vmcnt(8)" ::: "memory");
  __builtin_amdgcn_s_barrier();

  const int kb = (lane >> 4) << 4;
  bf16x8 ar[2][4][2];   // [mh][fi][ks]
  bf16x8 br[2][2][2];   // [nh][fj][ks]

  for (int j = 0; j < NT; ++j) {
    const char* buf = lds + (j & 1) * 65536;
    char* pbuf = lds + (j & 1) * 65536;       // tile j+2 -> same buffer
    const bool pf = (j + 2 < NT);
    const int kn = (j + 2) * 64;

    // ---- ph1: quadrant (mh0, nh0); reads A-mh0 (8) + B-nh0 (4) ----
#pragma unroll
    for (int fi = 0; fi < 4; ++fi)
#pragma unroll
      for (int ks = 0; ks < 2; ++ks)
        ar[0][fi][ks] = frag(buf + ks * 16384, wr * 128 + fi * 16 + (lane & 15), kb);
#pragma unroll
    for (int fj = 0; fj < 2; ++fj)
#pragma unroll
      for (int ks = 0; ks < 2; ++ks)
        br[0][fj][ks] = frag(buf + 32768 + ks * 16384, wc * 64 + fj * 16 + (lane & 15), kb);
    __builtin_amdgcn_s_barrier();
    asm volatile("s_waitcnt lgkmcnt(0)" ::: "memory");
    __builtin_amdgcn_s_setprio(1);
#pragma unroll
    for (int fi = 0; fi < 4; ++fi)
#pragma unroll
      for (int fj = 0; fj < 2; ++fj)
#pragma unroll
        for (int ks = 0; ks < 2; ++ks)
          acc[fi][fj] = __builtin_amdgcn_mfma_f32_16x16x32_bf16(ar[0][fi][ks], br[0][fj][ks], acc[fi][fj], 0, 0, 0);
    __builtin_amdgcn_s_setprio(0);
    __builtin_amdgcn_s_barrier();

    // ---- ph2: quadrant (mh1, nh1); reads A-mh1 (8) + B-nh1 (4) ----
#pragma unroll
    for (int fi = 0; fi < 4; ++fi)
#pragma unroll
      for (int ks = 0; ks < 2; ++ks)
        ar[1][fi][ks] = frag(buf + ks * 16384, wr * 128 + (fi + 4) * 16 + (lane & 15), kb);
#pragma unroll
    for (int fj = 0; fj < 2; ++fj)
#pragma unroll
      for (int ks = 0; ks < 2; ++ks)
        br[1][fj][ks] = frag(buf + 32768 + ks * 16384, wc * 64 + (fj + 2) * 16 + (lane & 15), kb);
    __builtin_amdgcn_s_barrier();
    asm volatile("s_waitcnt lgkmcnt(0)" ::: "memory");
    __builtin_amdgcn_s_setprio(1);
#pragma unroll
    for (int fi = 0; fi < 4; ++fi)
#pragma unroll
      for (int fj = 0; fj < 2; ++fj)
#pragma unroll
        for (int ks = 0; ks < 2; ++ks)
          acc[fi + 4][fj + 2] = __builtin_amdgcn_mfma_f32_16x16x32_bf16(ar[1][fi][ks], br[1][fj][ks], acc[fi + 4][fj + 2], 0, 0, 0);
    __builtin_amdgcn_s_setprio(0);
    __builtin_amdgcn_s_barrier();

    // ---- ph3: quadrant (mh0, nh1); stage A0,A1(j+2) (all reads done ph2) ----
    if (pf) {
      stage_slot(A, row0, kn,      pbuf);
      stage_slot(A, row0, kn + 32, pbuf + 16384);
    }
    __builtin_amdgcn_s_barrier();
    __builtin_amdgcn_s_setprio(1);
#pragma unroll
    for (int fi = 0; fi < 4; ++fi)
#pragma unroll
      for (int fj = 0; fj < 2; ++fj)
#pragma unroll
        for (int ks = 0; ks < 2; ++ks)
          acc[fi][fj + 2] = __builtin_amdgcn_mfma_f32_16x16x32_bf16(ar[0][fi][ks], br[1][fj][ks], acc[fi][fj + 2], 0, 0, 0);
    __builtin_amdgcn_s_setprio(0);
    __builtin_amdgcn_s_barrier();

    // ---- ph4: quadrant (mh1, nh0); stage B0,B1(j+2); counted vmcnt ----
    if (pf) {
      stage_slot(B, col0, kn,      pbuf + 32768);
      stage_slot(B, col0, kn + 32, pbuf + 49152);
      asm volatile("s_waitcnt vmcnt(8)" ::: "memory");
    } else if (j + 1 < NT) {
      asm volatile("s_waitcnt vmcnt(0)" ::: "memory");
    }
    __builtin_amdgcn_s_barrier();
    __builtin_amdgcn_s_setprio(1);
#pragma unroll
    for (int fi = 0; fi < 4; ++fi)
#pragma unroll
      for (int fj = 0; fj < 2; ++fj)
#pragma unroll
        for (int ks = 0; ks < 2; ++ks)
          acc[fi + 4][fj] = __builtin_amdgcn_mfma_f32_16x16x32_bf16(ar[1][fi][ks], br[0][fj][ks], acc[fi + 4][fj], 0, 0, 0);
    __builtin_amdgcn_s_setprio(0);
    __builtin_amdgcn_s_barrier();
  }

#pragma unroll
  for (int fi = 0; fi < 8; ++fi)
#pragma unroll
    for (int fj = 0; fj < 4; ++fj) {
      const int col = col0 + wc * 64 + fj * 16 + (lane & 15);
      const float bv = bias[col];
#pragma unroll
      for (int jj = 0; jj < 4; ++jj) {
        const int row = row0 + wr * 128 + fi * 16 + (lane >> 4) * 4 + jj;
        C[(size_t)row * N + col] = f2bf(acc[fi][fj][jj] + bv);
      }
    }
}

// ============ 3b. proj GEMM: 64x128 tile, BK=32, ring-4 (unchanged from R19) ====
__global__ __launch_bounds__(256, 2) void k_gemmProj(const unsigned short* __restrict__ A,
                                                     const unsigned short* __restrict__ B,
                                                     const float* __restrict__ bias,
                                                     float* __restrict__ out,
                                                     int M, int N, int K) {
  __shared__ __align__(16) char lds[49152];
  const int tid = threadIdx.x;
  const int lane = tid & 63;
  const int wid = tid >> 6;
  const int wr = wid >> 1, wc = wid & 1;
  const int row0 = blockIdx.y * 64;
  const int col0 = blockIdx.x * 128;
  const int NT = K >> 5;

  auto stageA = [&](int kcol0, char* slot) {
    const int off = tid * 16;
    const int pair = off >> 7;
    const int un = (off & 127) ^ ((pair & 7) << 4);
    const int grow = pair * 2 + (un >> 6);
    gload_lds16(A + (size_t)(row0 + grow) * K + kcol0 + ((un & 63) >> 1),
                slot + wid * 1024);
  };
  auto stageB = [&](int kcol0, char* slot) {
#pragma unroll
    for (int r = 0; r < 2; ++r) {
      const int off = r * 4096 + tid * 16;
      const int pair = off >> 7;
      const int un = (off & 127) ^ ((pair & 7) << 4);
      const int grow = pair * 2 + (un >> 6);
      gload_lds16(B + (size_t)(col0 + grow) * K + kcol0 + ((un & 63) >> 1),
                  slot + r * 4096 + wid * 1024);
    }
  };
  auto frag = [&](const char* slot, int r, int kb) -> bf16x8 {
    return *reinterpret_cast<const bf16x8*>(
        slot + (r >> 1) * 128 + ((((r & 1) << 6) + kb) ^ (((r >> 1) & 7) << 4)));
  };

  f32x4 acc[2][4];
#pragma unroll
  for (int i = 0; i < 2; ++i)
#pragma unroll
    for (int j = 0; j < 4; ++j) acc[i][j] = (f32x4){0.f, 0.f, 0.f, 0.f};

#pragma unroll
  for (int p = 0; p < 3; ++p) {
    stageA(p * 32, lds + p * 4096);
    stageB(p * 32, lds + 16384 + p * 8192);
  }
  asm volatile("s_waitcnt vmcnt(6)" ::: "memory");
  __builtin_amdgcn_s_barrier();

  const int kb = (lane >> 4) << 4;
  for (int j = 0; j < NT; ++j) {
    const char* baseA = lds + (j & 3) * 4096;
    const char* baseB = lds + 16384 + (j & 3) * 8192;
    bf16x8 af[2], bq[4];
#pragma unroll
    for (int fr = 0; fr < 2; ++fr) af[fr] = frag(baseA, wr * 32 + fr * 16 + (lane & 15), kb);
#pragma unroll
    for (int fc = 0; fc < 4; ++fc) bq[fc] = frag(baseB, wc * 64 + fc * 16 + (lane & 15), kb);

    const int jp = j + 3;
    if (jp < NT) {
      stageA(jp * 32, lds + (jp & 3) * 4096);
      stageB(jp * 32, lds + 16384 + (jp & 3) * 8192);
      asm volatile("s_waitcnt vmcnt(6)" ::: "memory");
    } else if (j + 2 < NT) {
      asm volatile("s_waitcnt vmcnt(3)" ::: "memory");
    } else if (j + 1 < NT) {
      asm volatile("s_waitcnt vmcnt(0)" ::: "memory");
    }
    if (j + 1 < NT) __builtin_amdgcn_s_barrier();

    __builtin_amdgcn_s_setprio(1);
#pragma unroll
    for (int fr = 0; fr < 2; ++fr)
#pragma unroll
      for (int fc = 0; fc < 4; ++fc)
        acc[fr][fc] = __builtin_amdgcn_mfma_f32_16x16x32_bf16(af[fr], bq[fc], acc[fr][fc], 0, 0, 0);
    __builtin_amdgcn_s_setprio(0);
  }

#pragma unroll
  for (int fr = 0; fr < 2; ++fr)
#pragma unroll
    for (int fc = 0; fc < 4; ++fc) {
      const int col = col0 + wc * 64 + fc * 16 + (lane & 15);
      const float bv = bias[col];
#pragma unroll
      for (int jj = 0; jj < 4; ++jj) {
        const int row = row0 + wr * 32 + fr * 16 + (lane >> 4) * 4 + jj;
        out[(size_t)row * N + col] = acc[fr][fc][jj] + bv;
      }
    }
}

// ============ 4. fused post: q/k RMSNorm+RoPE | v transpose (unchanged) ========
__global__ __launch_bounds__(256) void k_post(const unsigned short* __restrict__ qkv,
                                              const float* __restrict__ qw,
                                              const float* __restrict__ kw,
                                              const float* __restrict__ cosT,
                                              const float* __restrict__ sinT,
                                              unsigned short* __restrict__ qo,
                                              unsigned short* __restrict__ ko,
                                              unsigned short* __restrict__ vt2) {
  __shared__ __align__(16) unsigned short tile[64][136];
  if (blockIdx.x < 8192) {
    const int lane = threadIdx.x & 63;
    const int wid = threadIdx.x >> 6;
    const int pair = blockIdx.x * 4 + wid;
    const int n = pair >> 4, h = pair & 15;
    const float c = cosT[n * 64 + lane];
    const float s = sinT[n * 64 + lane];
#pragma unroll
    for (int sq = 0; sq < 2; ++sq) {
      const unsigned short* src = qkv + (size_t)n * 6144 + sq * 2048 + h * 128;
      const unsigned int vp = reinterpret_cast<const unsigned int*>(src)[lane];
      const float vx = bf2f((unsigned short)(vp & 0xffff));
      const float vy = bf2f((unsigned short)(vp >> 16));
      float ss = vx * vx + vy * vy;
#pragma unroll
      for (int m = 1; m < 64; m <<= 1) ss += __shfl_xor(ss, m, 64);
      const float r = rsqrtf(ss * (1.0f / 128.0f) + 1e-6f);
      float2 wv = reinterpret_cast<const float2*>(sq == 0 ? qw : kw)[lane];
      const float xr = vx * r * wv.x;
      const float xi = vy * r * wv.y;
      float orr = xr * c - xi * s;
      float oi  = xr * s + xi * c;
      if (sq == 0) { orr *= 0.08838834764831845f; oi *= 0.08838834764831845f; }
      unsigned short* dst = (sq == 0 ? qo : ko) + ((size_t)h * 2048 + n) * 128 + 2 * lane;
      const unsigned int pk = (unsigned int)f2bf(orr) | ((unsigned int)f2bf(oi) << 16);
      *reinterpret_cast<unsigned int*>(dst) = pk;
    }
  } else {
    const int idx = blockIdx.x - 8192;
    const int h = idx >> 5;
    const int n0 = (idx & 31) * 64;
    const int t = threadIdx.x;
    {
      const int row = t >> 2;
      const int c0 = (t & 3) * 32;
      const unsigned short* src = qkv + (size_t)(n0 + row) * 6144 + 4096 + h * 128 + c0;
#pragma unroll
      for (int j = 0; j < 32; j += 8)
        *reinterpret_cast<bf16x8*>(&tile[row][c0 + j]) =
            *reinterpret_cast<const bf16x8*>(src + j);
    }
    __syncthreads();
#pragma unroll
    for (int g4 = 0; g4 < 4; ++g4) {
      const int g = g4 * 256 + t;
      const int c = g >> 8;
      const int dblk = (g >> 6) & 3;
      const int p = g & 63;
      const int d = dblk * 32 + (p & 31);
      const int hi = p >> 5;
      bf16x8 o;
#pragma unroll
      for (int e = 0; e < 8; ++e) o[e] = (short)tile[c * 16 + hi * 8 + e][d];
      const size_t oidx = ((((size_t)h * 128 + (n0 >> 4) + c) * 4 + dblk) * 64 + p) * 8;
      *reinterpret_cast<bf16x8*>(vt2 + oidx) = o;
    }
  }
}

// ============ 5. flash attention (R13 structure, unchanged) ============
__global__ __launch_bounds__(256) void k_fattn(const unsigned short* __restrict__ q,
                                               const unsigned short* __restrict__ k,
                                               const unsigned short* __restrict__ vt2,
                                               unsigned short* __restrict__ Onorm,
                                               float* __restrict__ lseb) {
  __shared__ __align__(16) unsigned short Ks[2][64 * 128];
  __shared__ __align__(16) unsigned short Vs[2][64 * 128];
  const int lane = threadIdx.x & 63;
  const int wid = threadIdx.x >> 6;
  const int hi2 = lane >> 5;
  const int ql = lane & 31;
  const int bid = blockIdx.x;
  const int h = bid & 15;
  const int qb = (bid >> 4) & 15;
  const int ksp = bid >> 8;
  const int q0 = qb * 128 + wid * 32;
  const int kbase = ksp * 1024;

  auto stageK = [&](int buf, int kt2) {
#pragma unroll
    for (int r = 0; r < 4; ++r) {
      const int off = r * 4096 + (wid * 64 + lane) * 16;
      const int row = off >> 8;
      const int colb = (off & 255) ^ ((row & 15) << 4);
      gload_lds16(k + ((size_t)h * 2048 + kbase + kt2 * 64 + row) * 128 + (colb >> 1),
                  (char*)Ks[buf] + r * 4096 + wid * 1024);
    }
  };
  auto stageV = [&](int buf, int kt2) {
    const unsigned short* vbase = vt2 + ((size_t)h * 128 + (kbase >> 4) + kt2 * 4) * 2048;
#pragma unroll
    for (int r = 0; r < 4; ++r)
      gload_lds16(vbase + r * 2048 + (wid * 64 + lane) * 8,
                  (char*)Vs[buf] + r * 4096 + wid * 1024);
  };

  bf16x8 qf[8];
  {
    const unsigned short* qp = q + ((size_t)h * 2048 + q0 + ql) * 128 + hi2 * 8;
#pragma unroll
    for (int c = 0; c < 8; ++c) qf[c] = *reinterpret_cast<const bf16x8*>(qp + c * 16);
  }
  f32x16 O[4];
#pragma unroll
  for (int i = 0; i < 4; ++i)
#pragma unroll
    for (int j = 0; j < 16; ++j) O[i][j] = 0.f;
  float m = -1e30f, l = 0.f;

  stageK(0, 0);
  stageV(0, 0);
  asm volatile("s_waitcnt vmcnt(0)" ::: "memory");
  __builtin_amdgcn_s_barrier();

  const int kswz = (lane & 15) << 4;
  for (int kt = 0; kt < 16; ++kt) {
    const int cur = kt & 1;
    const bool pf = (kt + 1 < 16);
    if (pf) { stageK(cur ^ 1, kt + 1); stageV(cur ^ 1, kt + 1); }

    f32x16 s0, s1;
#pragma unroll
    for (int j = 0; j < 16; ++j) { s0[j] = 0.f; s1[j] = 0.f; }
    __builtin_amdgcn_s_setprio(1);
#pragma unroll
    for (int c = 0; c < 8; ++c) {
      bf16x8 a0 = *reinterpret_cast<const bf16x8*>(
          (const char*)Ks[cur] + ql * 256 + ((c * 32 + hi2 * 16) ^ kswz));
      s0 = __builtin_amdgcn_mfma_f32_32x32x16_bf16(a0, qf[c], s0, 0, 0, 0);
    }
#pragma unroll
    for (int c = 0; c < 8; ++c) {
      bf16x8 a1 = *reinterpret_cast<const bf16x8*>(
          (const char*)Ks[cur] + (32 + ql) * 256 + ((c * 32 + hi2 * 16) ^ kswz));
      s1 = __builtin_amdgcn_mfma_f32_32x32x16_bf16(a1, qf[c], s1, 0, 0, 0);
    }
    __builtin_amdgcn_s_setprio(0);

    float mt = s0[0];
#pragma unroll
    for (int j = 1; j < 16; ++j) mt = fmaxf(mt, s0[j]);
#pragma unroll
    for (int j = 0; j < 16; ++j) mt = fmaxf(mt, s1[j]);
    mt = fmaxf(mt, __shfl_xor(mt, 32, 64));

    if (!__all(mt <= m + 8.0f)) {
      const float mn = fmaxf(m, mt);
      const float al = __expf(m - mn);
      m = mn;
      l *= al;
#pragma unroll
      for (int i = 0; i < 4; ++i)
#pragma unroll
        for (int j = 0; j < 16; ++j) O[i][j] *= al;
    }
    float rs = 0.f;
#pragma unroll
    for (int j = 0; j < 16; ++j) {
      s0[j] = __expf(s0[j] - m); rs += s0[j];
      s1[j] = __expf(s1[j] - m); rs += s1[j];
    }
    rs += __shfl_xor(rs, 32, 64);
    l += rs;

    bf16x8 pfr[4];
#pragma unroll
    for (int half = 0; half < 2; ++half) {
      const f32x16& sv = half ? s1 : s0;
      unsigned a[8];
#pragma unroll
      for (int j2 = 0; j2 < 8; ++j2) a[j2] = cvtpk(sv[2 * j2], sv[2 * j2 + 1]);
      pswap(a[0], a[2]);
      pswap(a[1], a[3]);
      pswap(a[4], a[6]);
      pswap(a[5], a[7]);
      union { uint4 u; bf16x8 v; } p0, p1;
      p0.u.x = a[0]; p0.u.y = a[1]; p0.u.z = a[2]; p0.u.w = a[3];
      p1.u.x = a[4]; p1.u.y = a[5]; p1.u.z = a[6]; p1.u.w = a[7];
      pfr[half * 2 + 0] = p0.v;
      pfr[half * 2 + 1] = p1.v;
    }

    __builtin_amdgcn_s_setprio(1);
#pragma unroll
    for (int dblk = 0; dblk < 4; ++dblk) {
#pragma unroll
      for (int c2 = 0; c2 < 4; ++c2) {
        bf16x8 va = *reinterpret_cast<const bf16x8*>(
            (const char*)Vs[cur] + ((c2 * 4 + dblk) * 64 + lane) * 16);
        O[dblk] = __builtin_amdgcn_mfma_f32_32x32x16_bf16(va, pfr[c2], O[dblk], 0, 0, 0);
      }
    }
    __builtin_amdgcn_s_setprio(0);

    if (pf) {
      asm volatile("s_waitcnt vmcnt(0)" ::: "memory");
      __builtin_amdgcn_s_barrier();
    }
  }

  const float rl = 1.0f / l;
  const int n = q0 + ql;
  unsigned short* ob = Onorm + (((size_t)(ksp * 16 + h) * 2048) + n) * 128;
#pragma unroll
  for (int dblk = 0; dblk < 4; ++dblk)
#pragma unroll
    for (int a = 0; a < 4; ++a) {
      uint2 w;
      w.x = (unsigned)f2bf(O[dblk][a * 4 + 0] * rl) | ((unsigned)f2bf(O[dblk][a * 4 + 1] * rl) << 16);
      w.y = (unsigned)f2bf(O[dblk][a * 4 + 2] * rl) | ((unsigned)f2bf(O[dblk][a * 4 + 3] * rl) << 16);
      *reinterpret_cast<uint2*>(ob + dblk * 32 + a * 8 + hi2 * 4) = w;
    }
  if (hi2 == 0)
    lseb[(size_t)(ksp * 16 + h) * 2048 + n] = m + logf(l);
}

// ============ 6. merge the two key-split partials ============
__global__ __launch_bounds__(256) void k_merge(const unsigned short* __restrict__ Onorm,
                                               const float* __restrict__ lseb,
                                               unsigned short* __restrict__ att) {
  const int idx = blockIdx.x * 256 + threadIdx.x;
  const int n = idx >> 8;
  const int r = idx & 255;
  const int h = r >> 4;
  const int d0 = (r & 15) * 8;
  const float l0 = lseb[(size_t)h * 2048 + n];
  const float l1 = lseb[(size_t)(16 + h) * 2048 + n];
  const float M = fmaxf(l0, l1);
  float w0 = __expf(l0 - M), w1 = __expf(l1 - M);
  const float inv = 1.0f / (w0 + w1);
  w0 *= inv; w1 *= inv;
  const bf16x8 o0 = *reinterpret_cast<const bf16x8*>(
      Onorm + ((size_t)h * 2048 + n) * 128 + d0);
  const bf16x8 o1 = *reinterpret_cast<const bf16x8*>(
      Onorm + ((size_t)(16 + h) * 2048 + n) * 128 + d0);
  bf16x8 o;
#pragma unroll
  for (int e = 0; e < 8; ++e)
    o[e] = (short)f2bf(bf2f((unsigned short)o0[e]) * w0 + bf2f((unsigned short)o1[e]) * w1);
  *reinterpret_cast<bf16x8*>(att + (size_t)n * 2048 + h * 128 + d0) = o;
}

extern "C" void kernel_launch(void* const* d_in, const int* in_sizes, int n_in,
                              void* d_out, int out_size, void* d_ws, size_t ws_size,
                              hipStream_t stream) {
  (void)in_sizes; (void)n_in; (void)out_size; (void)ws_size;
  const float* x      = (const float*)d_in[0];
  const float* qkv_w  = (const float*)d_in[1];
  const float* qkv_b  = (const float*)d_in[2];
  const float* proj_w = (const float*)d_in[3];
  const float* proj_b = (const float*)d_in[4];
  const float* q_nw   = (const float*)d_in[5];
  const float* k_nw   = (const float*)d_in[6];
  const int* h_dim    = (const int*)d_in[8];
  const int* w_dim    = (const int*)d_in[9];
  float* out = (float*)d_out;

  char* ws = (char*)d_ws;
  size_t off = 0;
  auto carve = [&](size_t bytes) -> void* {
    void* p = ws + off;
    off += (bytes + 255) & ~(size_t)255;
    return p;
  };
  unsigned short* x_bf   = (unsigned short*)carve(2048ull * 2048 * 2);
  unsigned short* w1_bf  = (unsigned short*)carve(6144ull * 2048 * 2);
  unsigned short* w2_bf  = (unsigned short*)carve(2048ull * 2048 * 2);
  unsigned short* qkvb   = (unsigned short*)carve(2048ull * 6144 * 2);
  unsigned short* q_bf   = (unsigned short*)carve(16ull * 2048 * 128 * 2);
  unsigned short* k_bf   = (unsigned short*)carve(16ull * 2048 * 128 * 2);
  unsigned short* vt2_bf = (unsigned short*)carve(16ull * 2048 * 128 * 2);
  unsigned short* att_bf = (unsigned short*)carve(2048ull * 2048 * 2);
  unsigned short* on_bf  = (unsigned short*)carve(2ull * 16 * 2048 * 128 * 2);
  float*          lseb   = (float*)carve(2ull * 16 * 2048 * 4);
  float*          cosT   = (float*)carve(2048ull * 64 * 4);
  float*          sinT   = (float*)carve(2048ull * 64 * 4);

  hipLaunchKernelGGL(k_cvt3, dim3(2048), dim3(256), 0, stream,
                     x, x_bf, 2048 * 2048 / 4,
                     qkv_w, w1_bf, 6144 * 2048 / 4,
                     proj_w, w2_bf, 2048 * 2048 / 4,
                     cosT, sinT, h_dim, w_dim);
  hipLaunchKernelGGL(k_gemmQKV8, dim3(192), dim3(512), 0, stream,
                     x_bf, w1_bf, qkv_b, qkvb, 2048, 6144, 2048);
  hipLaunchKernelGGL(k_post, dim3(8704), dim3(256), 0, stream,
                     qkvb, q_nw, k_nw, cosT, sinT, q_bf, k_bf, vt2_bf);
  hipLaunchKernelGGL(k_fattn, dim3(512), dim3(256), 0, stream,
                     q_bf, k_bf, vt2_bf, on_bf, lseb);
  hipLaunchKernelGGL(k_merge, dim3(2048), dim3(256), 0, stream, on_bf, lseb, att_bf);
  hipLaunchKernelGGL(k_gemmProj, dim3(16, 32), dim3(256), 0, stream,
                     att_bf, w2_bf, proj_b, out, 2048, 2048, 2048);
}

// Round 21
// 166.335 us; speedup vs baseline: 1.0464x; 1.0464x over previous
//
#include <hip/hip_runtime.h>
#include <hip/hip_bf16.h>
#include <cstdint>
#include <cstddef>

typedef __attribute__((ext_vector_type(8))) short bf16x8;
typedef __attribute__((ext_vector_type(4))) float f32x4;
typedef __attribute__((ext_vector_type(16))) float f32x16;

#define AS1 __attribute__((address_space(1)))
#define AS3 __attribute__((address_space(3)))

__device__ __forceinline__ void gload_lds16(const void* g, void* l) {
  __builtin_amdgcn_global_load_lds((const AS1 void*)g, (AS3 void*)l, 16, 0, 0);
}

__device__ __forceinline__ unsigned short f2bf(float x) {
  __hip_bfloat16 h = __float2bfloat16(x);
  return __builtin_bit_cast(unsigned short, h);
}
__device__ __forceinline__ float bf2f(unsigned short u) {
  return __builtin_bit_cast(float, (unsigned int)u << 16);
}
__device__ __forceinline__ unsigned cvtpk(float a, float b) {
  unsigned r;
  asm("v_cvt_pk_bf16_f32 %0, %1, %2" : "=v"(r) : "v"(a), "v"(b));
  return r;
}
// v_permlane32_swap_b32 vdst, vsrc: vdst[lanes 32..63] <-> vsrc[lanes 0..31]
__device__ __forceinline__ void pswap(unsigned& x, unsigned& y) {
  asm volatile("v_permlane32_swap_b32 %0, %1" : "+v"(x), "+v"(y));
}

// ============ 1. fused: f32->bf16 converts (x, qkv_w, proj_w) + RoPE tables ====
__global__ __launch_bounds__(256) void k_cvt3(const float* __restrict__ a, unsigned short* __restrict__ ao, int na4,
                                              const float* __restrict__ b, unsigned short* __restrict__ bo, int nb4,
                                              const float* __restrict__ c, unsigned short* __restrict__ co, int nc4,
                                              float* __restrict__ cosT, float* __restrict__ sinT,
                                              const int* __restrict__ hdim, const int* __restrict__ wdim) {
  const int stride = gridDim.x * 256;
  for (int i = blockIdx.x * 256 + threadIdx.x; i < na4; i += stride) {
    float4 v = reinterpret_cast<const float4*>(a)[i];
    ushort4 o; o.x = f2bf(v.x); o.y = f2bf(v.y); o.z = f2bf(v.z); o.w = f2bf(v.w);
    reinterpret_cast<ushort4*>(ao)[i] = o;
  }
  for (int i = blockIdx.x * 256 + threadIdx.x; i < nb4; i += stride) {
    float4 v = reinterpret_cast<const float4*>(b)[i];
    ushort4 o; o.x = f2bf(v.x); o.y = f2bf(v.y); o.z = f2bf(v.z); o.w = f2bf(v.w);
    reinterpret_cast<ushort4*>(bo)[i] = o;
  }
  for (int i = blockIdx.x * 256 + threadIdx.x; i < nc4; i += stride) {
    float4 v = reinterpret_cast<const float4*>(c)[i];
    ushort4 o; o.x = f2bf(v.x); o.y = f2bf(v.y); o.z = f2bf(v.z); o.w = f2bf(v.w);
    reinterpret_cast<ushort4*>(co)[i] = o;
  }
  const int H = *hdim, W = *wdim;
  for (int idx = blockIdx.x * 256 + threadIdx.x; idx < 2048 * 64; idx += stride) {
    const int n = idx >> 6, j = idx & 63;
    const int w = n % W;
    const int rem = n / W;
    const int h = rem % H;
    const int t = rem / H;
    float pos, i2, d;
    if (j < 22)      { pos = (float)t; i2 = (float)(2 * j);        d = 44.f; }
    else if (j < 43) { pos = (float)h; i2 = (float)(2 * (j - 22)); d = 42.f; }
    else             { pos = (float)w; i2 = (float)(2 * (j - 43)); d = 42.f; }
    const float ang = pos * powf(10000.0f, -i2 / d);
    cosT[idx] = cosf(ang);
    sinT[idx] = sinf(ang);
  }
}

// ============ 3a. QKV GEMM: 128x192, BK=32, ring-4 (R19 verified) ============
__global__ __launch_bounds__(256, 2) void k_gemmQKV(const unsigned short* __restrict__ A,
                                                    const unsigned short* __restrict__ B,
                                                    const float* __restrict__ bias,
                                                    unsigned short* __restrict__ C,
                                                    int M, int N, int K) {
  __shared__ __align__(16) char lds[81920];
  const int tid = threadIdx.x;
  const int lane = tid & 63;
  const int wid = tid >> 6;
  const int wr = wid >> 1, wc = wid & 1;

  const int xcd = blockIdx.x & 7;
  const int t0 = blockIdx.x >> 3;
  const int bx = xcd * 4 + (t0 & 3);
  const int by = t0 >> 2;
  const int row0 = by * 128, col0 = bx * 192;
  const int NT = K >> 5;

  auto stageA = [&](int kcol0, char* slot) {
#pragma unroll
    for (int r = 0; r < 2; ++r) {
      const int off = r * 4096 + tid * 16;
      const int pair = off >> 7;
      const int un = (off & 127) ^ ((pair & 7) << 4);
      const int grow = pair * 2 + (un >> 6);
      gload_lds16(A + (size_t)(row0 + grow) * K + kcol0 + ((un & 63) >> 1),
                  slot + r * 4096 + wid * 1024);
    }
  };
  auto stageB = [&](int kcol0, char* slot) {
#pragma unroll
    for (int r = 0; r < 3; ++r) {
      const int off = r * 4096 + tid * 16;
      const int pair = off >> 7;
      const int un = (off & 127) ^ ((pair & 7) << 4);
      const int grow = pair * 2 + (un >> 6);
      gload_lds16(B + (size_t)(col0 + grow) * K + kcol0 + ((un & 63) >> 1),
                  slot + r * 4096 + wid * 1024);
    }
  };
  auto frag = [&](const char* slot, int r, int kb) -> bf16x8 {
    return *reinterpret_cast<const bf16x8*>(
        slot + (r >> 1) * 128 + ((((r & 1) << 6) + kb) ^ (((r >> 1) & 7) << 4)));
  };

  f32x4 acc[4][6];
#pragma unroll
  for (int i = 0; i < 4; ++i)
#pragma unroll
    for (int j = 0; j < 6; ++j) acc[i][j] = (f32x4){0.f, 0.f, 0.f, 0.f};

#pragma unroll
  for (int p = 0; p < 3; ++p) {
    stageA(p * 32, lds + p * 8192);
    stageB(p * 32, lds + 32768 + p * 12288);
  }
  asm volatile("s_waitcnt vmcnt(10)" ::: "memory");
  __builtin_amdgcn_s_barrier();

  const int kb = (lane >> 4) << 4;
  for (int j = 0; j < NT; ++j) {
    const char* baseA = lds + (j & 3) * 8192;
    const char* baseB = lds + 32768 + (j & 3) * 12288;
    bf16x8 af[4], bq[6];
#pragma unroll
    for (int fr = 0; fr < 4; ++fr) af[fr] = frag(baseA, wr * 64 + fr * 16 + (lane & 15), kb);
#pragma unroll
    for (int fc = 0; fc < 6; ++fc) bq[fc] = frag(baseB, wc * 96 + fc * 16 + (lane & 15), kb);

    const int jp = j + 3;
    if (jp < NT) {
      stageA(jp * 32, lds + (jp & 3) * 8192);
      stageB(jp * 32, lds + 32768 + (jp & 3) * 12288);
      asm volatile("s_waitcnt vmcnt(10)" ::: "memory");
    } else if (j + 2 < NT) {
      asm volatile("s_waitcnt vmcnt(5)" ::: "memory");
    } else if (j + 1 < NT) {
      asm volatile("s_waitcnt vmcnt(0)" ::: "memory");
    }
    if (j + 1 < NT) __builtin_amdgcn_s_barrier();

    __builtin_amdgcn_s_setprio(1);
#pragma unroll
    for (int fr = 0; fr < 4; ++fr)
#pragma unroll
      for (int fc = 0; fc < 6; ++fc)
        acc[fr][fc] = __builtin_amdgcn_mfma_f32_16x16x32_bf16(af[fr], bq[fc], acc[fr][fc], 0, 0, 0);
    __builtin_amdgcn_s_setprio(0);
  }

#pragma unroll
  for (int fr = 0; fr < 4; ++fr)
#pragma unroll
    for (int fc = 0; fc < 6; ++fc) {
      const int col = col0 + wc * 96 + fc * 16 + (lane & 15);
      const float bv = bias[col];
#pragma unroll
      for (int jj = 0; jj < 4; ++jj) {
        const int row = row0 + wr * 64 + fr * 16 + (lane >> 4) * 4 + jj;
        C[(size_t)row * N + col] = f2bf(acc[fr][fc][jj] + bv);
      }
    }
}

// ============ 3b. proj GEMM: 64x128 tile, BK=32, ring-4, NO split-K ============
__global__ __launch_bounds__(256, 2) void k_gemmProj(const unsigned short* __restrict__ A,
                                                     const unsigned short* __restrict__ B,
                                                     const float* __restrict__ bias,
                                                     float* __restrict__ out,
                                                     int M, int N, int K) {
  __shared__ __align__(16) char lds[49152];
  const int tid = threadIdx.x;
  const int lane = tid & 63;
  const int wid = tid >> 6;
  const int wr = wid >> 1, wc = wid & 1;
  const int row0 = blockIdx.y * 64;
  const int col0 = blockIdx.x * 128;
  const int NT = K >> 5;

  auto stageA = [&](int kcol0, char* slot) {
    const int off = tid * 16;
    const int pair = off >> 7;
    const int un = (off & 127) ^ ((pair & 7) << 4);
    const int grow = pair * 2 + (un >> 6);
    gload_lds16(A + (size_t)(row0 + grow) * K + kcol0 + ((un & 63) >> 1),
                slot + wid * 1024);
  };
  auto stageB = [&](int kcol0, char* slot) {
#pragma unroll
    for (int r = 0; r < 2; ++r) {
      const int off = r * 4096 + tid * 16;
      const int pair = off >> 7;
      const int un = (off & 127) ^ ((pair & 7) << 4);
      const int grow = pair * 2 + (un >> 6);
      gload_lds16(B + (size_t)(col0 + grow) * K + kcol0 + ((un & 63) >> 1),
                  slot + r * 4096 + wid * 1024);
    }
  };
  auto frag = [&](const char* slot, int r, int kb) -> bf16x8 {
    return *reinterpret_cast<const bf16x8*>(
        slot + (r >> 1) * 128 + ((((r & 1) << 6) + kb) ^ (((r >> 1) & 7) << 4)));
  };

  f32x4 acc[2][4];
#pragma unroll
  for (int i = 0; i < 2; ++i)
#pragma unroll
    for (int j = 0; j < 4; ++j) acc[i][j] = (f32x4){0.f, 0.f, 0.f, 0.f};

#pragma unroll
  for (int p = 0; p < 3; ++p) {
    stageA(p * 32, lds + p * 4096);
    stageB(p * 32, lds + 16384 + p * 8192);
  }
  asm volatile("s_waitcnt vmcnt(6)" ::: "memory");
  __builtin_amdgcn_s_barrier();

  const int kb = (lane >> 4) << 4;
  for (int j = 0; j < NT; ++j) {
    const char* baseA = lds + (j & 3) * 4096;
    const char* baseB = lds + 16384 + (j & 3) * 8192;
    bf16x8 af[2], bq[4];
#pragma unroll
    for (int fr = 0; fr < 2; ++fr) af[fr] = frag(baseA, wr * 32 + fr * 16 + (lane & 15), kb);
#pragma unroll
    for (int fc = 0; fc < 4; ++fc) bq[fc] = frag(baseB, wc * 64 + fc * 16 + (lane & 15), kb);

    const int jp = j + 3;
    if (jp < NT) {
      stageA(jp * 32, lds + (jp & 3) * 4096);
      stageB(jp * 32, lds + 16384 + (jp & 3) * 8192);
      asm volatile("s_waitcnt vmcnt(6)" ::: "memory");
    } else if (j + 2 < NT) {
      asm volatile("s_waitcnt vmcnt(3)" ::: "memory");
    } else if (j + 1 < NT) {
      asm volatile("s_waitcnt vmcnt(0)" ::: "memory");
    }
    if (j + 1 < NT) __builtin_amdgcn_s_barrier();

    __builtin_amdgcn_s_setprio(1);
#pragma unroll
    for (int fr = 0; fr < 2; ++fr)
#pragma unroll
      for (int fc = 0; fc < 4; ++fc)
        acc[fr][fc] = __builtin_amdgcn_mfma_f32_16x16x32_bf16(af[fr], bq[fc], acc[fr][fc], 0, 0, 0);
    __builtin_amdgcn_s_setprio(0);
  }

#pragma unroll
  for (int fr = 0; fr < 2; ++fr)
#pragma unroll
    for (int fc = 0; fc < 4; ++fc) {
      const int col = col0 + wc * 64 + fc * 16 + (lane & 15);
      const float bv = bias[col];
#pragma unroll
      for (int jj = 0; jj < 4; ++jj) {
        const int row = row0 + wr * 32 + fr * 16 + (lane >> 4) * 4 + jj;
        out[(size_t)row * N + col] = acc[fr][fc][jj] + bv;
      }
    }
}

// ============ 4. fused post: q/k RMSNorm+RoPE (blocks < 8192) | v transpose ====
__global__ __launch_bounds__(256) void k_post(const unsigned short* __restrict__ qkv,
                                              const float* __restrict__ qw,
                                              const float* __restrict__ kw,
                                              const float* __restrict__ cosT,
                                              const float* __restrict__ sinT,
                                              unsigned short* __restrict__ qo,
                                              unsigned short* __restrict__ ko,
                                              unsigned short* __restrict__ vt2) {
  __shared__ __align__(16) unsigned short tile[64][136];
  if (blockIdx.x < 8192) {
    const int lane = threadIdx.x & 63;
    const int wid = threadIdx.x >> 6;
    const int pair = blockIdx.x * 4 + wid;
    const int n = pair >> 4, h = pair & 15;
    const float c = cosT[n * 64 + lane];
    const float s = sinT[n * 64 + lane];
#pragma unroll
    for (int sq = 0; sq < 2; ++sq) {
      const unsigned short* src = qkv + (size_t)n * 6144 + sq * 2048 + h * 128;
      const unsigned int vp = reinterpret_cast<const unsigned int*>(src)[lane];
      const float vx = bf2f((unsigned short)(vp & 0xffff));
      const float vy = bf2f((unsigned short)(vp >> 16));
      float ss = vx * vx + vy * vy;
#pragma unroll
      for (int m = 1; m < 64; m <<= 1) ss += __shfl_xor(ss, m, 64);
      const float r = rsqrtf(ss * (1.0f / 128.0f) + 1e-6f);
      float2 wv = reinterpret_cast<const float2*>(sq == 0 ? qw : kw)[lane];
      const float xr = vx * r * wv.x;
      const float xi = vy * r * wv.y;
      float orr = xr * c - xi * s;
      float oi  = xr * s + xi * c;
      if (sq == 0) { orr *= 0.08838834764831845f; oi *= 0.08838834764831845f; }
      unsigned short* dst = (sq == 0 ? qo : ko) + ((size_t)h * 2048 + n) * 128 + 2 * lane;
      const unsigned int pk = (unsigned int)f2bf(orr) | ((unsigned int)f2bf(oi) << 16);
      *reinterpret_cast<unsigned int*>(dst) = pk;
    }
  } else {
    const int idx = blockIdx.x - 8192;     // 0..511
    const int h = idx >> 5;
    const int n0 = (idx & 31) * 64;
    const int t = threadIdx.x;
    {
      const int row = t >> 2;
      const int c0 = (t & 3) * 32;
      const unsigned short* src = qkv + (size_t)(n0 + row) * 6144 + 4096 + h * 128 + c0;
#pragma unroll
      for (int j = 0; j < 32; j += 8)
        *reinterpret_cast<bf16x8*>(&tile[row][c0 + j]) =
            *reinterpret_cast<const bf16x8*>(src + j);
    }
    __syncthreads();
#pragma unroll
    for (int g4 = 0; g4 < 4; ++g4) {
      const int g = g4 * 256 + t;
      const int c = g >> 8;
      const int dblk = (g >> 6) & 3;
      const int p = g & 63;
      const int d = dblk * 32 + (p & 31);
      const int hi = p >> 5;
      bf16x8 o;
#pragma unroll
      for (int e = 0; e < 8; ++e) o[e] = (short)tile[c * 16 + hi * 8 + e][d];
      const size_t oidx = ((((size_t)h * 128 + (n0 >> 4) + c) * 4 + dblk) * 64 + p) * 8;
      *reinterpret_cast<bf16x8*>(vt2 + oidx) = o;
    }
  }
}

// ============ 5. flash attention (R13 structure) ============
__global__ __launch_bounds__(256) void k_fattn(const unsigned short* __restrict__ q,
                                               const unsigned short* __restrict__ k,
                                               const unsigned short* __restrict__ vt2,
                                               unsigned short* __restrict__ Onorm,
                                               float* __restrict__ lseb) {
  __shared__ __align__(16) unsigned short Ks[2][64 * 128];
  __shared__ __align__(16) unsigned short Vs[2][64 * 128];
  const int lane = threadIdx.x & 63;
  const int wid = threadIdx.x >> 6;
  const int hi2 = lane >> 5;
  const int ql = lane & 31;
  const int bid = blockIdx.x;
  const int h = bid & 15;
  const int qb = (bid >> 4) & 15;
  const int ksp = bid >> 8;
  const int q0 = qb * 128 + wid * 32;
  const int kbase = ksp * 1024;

  auto stageK = [&](int buf, int kt2) {
#pragma unroll
    for (int r = 0; r < 4; ++r) {
      const int off = r * 4096 + (wid * 64 + lane) * 16;
      const int row = off >> 8;
      const int colb = (off & 255) ^ ((row & 15) << 4);
      gload_lds16(k + ((size_t)h * 2048 + kbase + kt2 * 64 + row) * 128 + (colb >> 1),
                  (char*)Ks[buf] + r * 4096 + wid * 1024);
    }
  };
  auto stageV = [&](int buf, int kt2) {
    const unsigned short* vbase = vt2 + ((size_t)h * 128 + (kbase >> 4) + kt2 * 4) * 2048;
#pragma unroll
    for (int r = 0; r < 4; ++r)
      gload_lds16(vbase + r * 2048 + (wid * 64 + lane) * 8,
                  (char*)Vs[buf] + r * 4096 + wid * 1024);
  };

  bf16x8 qf[8];
  {
    const unsigned short* qp = q + ((size_t)h * 2048 + q0 + ql) * 128 + hi2 * 8;
#pragma unroll
    for (int c = 0; c < 8; ++c) qf[c] = *reinterpret_cast<const bf16x8*>(qp + c * 16);
  }
  f32x16 O[4];
#pragma unroll
  for (int i = 0; i < 4; ++i)
#pragma unroll
    for (int j = 0; j < 16; ++j) O[i][j] = 0.f;
  float m = -1e30f, l = 0.f;

  stageK(0, 0);
  stageV(0, 0);
  asm volatile("s_waitcnt vmcnt(0)" ::: "memory");
  __builtin_amdgcn_s_barrier();

  const int kswz = (lane & 15) << 4;
  for (int kt = 0; kt < 16; ++kt) {
    const int cur = kt & 1;
    const bool pf = (kt + 1 < 16);
    if (pf) { stageK(cur ^ 1, kt + 1); stageV(cur ^ 1, kt + 1); }

    f32x16 s0, s1;
#pragma unroll
    for (int j = 0; j < 16; ++j) { s0[j] = 0.f; s1[j] = 0.f; }
    __builtin_amdgcn_s_setprio(1);
#pragma unroll
    for (int c = 0; c < 8; ++c) {
      bf16x8 a0 = *reinterpret_cast<const bf16x8*>(
          (const char*)Ks[cur] + ql * 256 + ((c * 32 + hi2 * 16) ^ kswz));
      s0 = __builtin_amdgcn_mfma_f32_32x32x16_bf16(a0, qf[c], s0, 0, 0, 0);
    }
#pragma unroll
    for (int c = 0; c < 8; ++c) {
      bf16x8 a1 = *reinterpret_cast<const bf16x8*>(
          (const char*)Ks[cur] + (32 + ql) * 256 + ((c * 32 + hi2 * 16) ^ kswz));
      s1 = __builtin_amdgcn_mfma_f32_32x32x16_bf16(a1, qf[c], s1, 0, 0, 0);
    }
    __builtin_amdgcn_s_setprio(0);

    float mt = s0[0];
#pragma unroll
    for (int j = 1; j < 16; ++j) mt = fmaxf(mt, s0[j]);
#pragma unroll
    for (int j = 0; j < 16; ++j) mt = fmaxf(mt, s1[j]);
    mt = fmaxf(mt, __shfl_xor(mt, 32, 64));

    if (!__all(mt <= m + 8.0f)) {
      const float mn = fmaxf(m, mt);
      const float al = __expf(m - mn);
      m = mn;
      l *= al;
#pragma unroll
      for (int i = 0; i < 4; ++i)
#pragma unroll
        for (int j = 0; j < 16; ++j) O[i][j] *= al;
    }
    float rs = 0.f;
#pragma unroll
    for (int j = 0; j < 16; ++j) {
      s0[j] = __expf(s0[j] - m); rs += s0[j];
      s1[j] = __expf(s1[j] - m); rs += s1[j];
    }
    rs += __shfl_xor(rs, 32, 64);
    l += rs;

    bf16x8 pfr[4];
#pragma unroll
    for (int half = 0; half < 2; ++half) {
      const f32x16& sv = half ? s1 : s0;
      unsigned a[8];
#pragma unroll
      for (int j2 = 0; j2 < 8; ++j2) a[j2] = cvtpk(sv[2 * j2], sv[2 * j2 + 1]);
      pswap(a[0], a[2]);
      pswap(a[1], a[3]);
      pswap(a[4], a[6]);
      pswap(a[5], a[7]);
      union { uint4 u; bf16x8 v; } p0, p1;
      p0.u.x = a[0]; p0.u.y = a[1]; p0.u.z = a[2]; p0.u.w = a[3];
      p1.u.x = a[4]; p1.u.y = a[5]; p1.u.z = a[6]; p1.u.w = a[7];
      pfr[half * 2 + 0] = p0.v;
      pfr[half * 2 + 1] = p1.v;
    }

    __builtin_amdgcn_s_setprio(1);
#pragma unroll
    for (int dblk = 0; dblk < 4; ++dblk) {
#pragma unroll
      for (int c2 = 0; c2 < 4; ++c2) {
        bf16x8 va = *reinterpret_cast<const bf16x8*>(
            (const char*)Vs[cur] + ((c2 * 4 + dblk) * 64 + lane) * 16);
        O[dblk] = __builtin_amdgcn_mfma_f32_32x32x16_bf16(va, pfr[c2], O[dblk], 0, 0, 0);
      }
    }
    __builtin_amdgcn_s_setprio(0);

    if (pf) {
      asm volatile("s_waitcnt vmcnt(0)" ::: "memory");
      __builtin_amdgcn_s_barrier();
    }
  }

  const float rl = 1.0f / l;
  const int n = q0 + ql;
  unsigned short* ob = Onorm + (((size_t)(ksp * 16 + h) * 2048) + n) * 128;
#pragma unroll
  for (int dblk = 0; dblk < 4; ++dblk)
#pragma unroll
    for (int a = 0; a < 4; ++a) {
      uint2 w;
      w.x = (unsigned)f2bf(O[dblk][a * 4 + 0] * rl) | ((unsigned)f2bf(O[dblk][a * 4 + 1] * rl) << 16);
      w.y = (unsigned)f2bf(O[dblk][a * 4 + 2] * rl) | ((unsigned)f2bf(O[dblk][a * 4 + 3] * rl) << 16);
      *reinterpret_cast<uint2*>(ob + dblk * 32 + a * 8 + hi2 * 4) = w;
    }
  if (hi2 == 0)
    lseb[(size_t)(ksp * 16 + h) * 2048 + n] = m + logf(l);
}

// ============ 6. merge the two key-split partials ============
__global__ __launch_bounds__(256) void k_merge(const unsigned short* __restrict__ Onorm,
                                               const float* __restrict__ lseb,
                                               unsigned short* __restrict__ att) {
  const int idx = blockIdx.x * 256 + threadIdx.x;
  const int n = idx >> 8;
  const int r = idx & 255;
  const int h = r >> 4;
  const int d0 = (r & 15) * 8;
  const float l0 = lseb[(size_t)h * 2048 + n];
  const float l1 = lseb[(size_t)(16 + h) * 2048 + n];
  const float M = fmaxf(l0, l1);
  float w0 = __expf(l0 - M), w1 = __expf(l1 - M);
  const float inv = 1.0f / (w0 + w1);
  w0 *= inv; w1 *= inv;
  const bf16x8 o0 = *reinterpret_cast<const bf16x8*>(
      Onorm + ((size_t)h * 2048 + n) * 128 + d0);
  const bf16x8 o1 = *reinterpret_cast<const bf16x8*>(
      Onorm + ((size_t)(16 + h) * 2048 + n) * 128 + d0);
  bf16x8 o;
#pragma unroll
  for (int e = 0; e < 8; ++e)
    o[e] = (short)f2bf(bf2f((unsigned short)o0[e]) * w0 + bf2f((unsigned short)o1[e]) * w1);
  *reinterpret_cast<bf16x8*>(att + (size_t)n * 2048 + h * 128 + d0) = o;
}

extern "C" void kernel_launch(void* const* d_in, const int* in_sizes, int n_in,
                              void* d_out, int out_size, void* d_ws, size_t ws_size,
                              hipStream_t stream) {
  (void)in_sizes; (void)n_in; (void)out_size; (void)ws_size;
  const float* x      = (const float*)d_in[0];
  const float* qkv_w  = (const float*)d_in[1];
  const float* qkv_b  = (const float*)d_in[2];
  const float* proj_w = (const float*)d_in[3];
  const float* proj_b = (const float*)d_in[4];
  const float* q_nw   = (const float*)d_in[5];
  const float* k_nw   = (const float*)d_in[6];
  const int* h_dim    = (const int*)d_in[8];
  const int* w_dim    = (const int*)d_in[9];
  float* out = (float*)d_out;

  char* ws = (char*)d_ws;
  size_t off = 0;
  auto carve = [&](size_t bytes) -> void* {
    void* p = ws + off;
    off += (bytes + 255) & ~(size_t)255;
    return p;
  };
  unsigned short* x_bf   = (unsigned short*)carve(2048ull * 2048 * 2);
  unsigned short* w1_bf  = (unsigned short*)carve(6144ull * 2048 * 2);
  unsigned short* w2_bf  = (unsigned short*)carve(2048ull * 2048 * 2);
  unsigned short* qkvb   = (unsigned short*)carve(2048ull * 6144 * 2);
  unsigned short* q_bf   = (unsigned short*)carve(16ull * 2048 * 128 * 2);
  unsigned short* k_bf   = (unsigned short*)carve(16ull * 2048 * 128 * 2);
  unsigned short* vt2_bf = (unsigned short*)carve(16ull * 2048 * 128 * 2);
  unsigned short* att_bf = (unsigned short*)carve(2048ull * 2048 * 2);
  unsigned short* on_bf  = (unsigned short*)carve(2ull * 16 * 2048 * 128 * 2);
  float*          lseb   = (float*)carve(2ull * 16 * 2048 * 4);
  float*          cosT   = (float*)carve(2048ull * 64 * 4);
  float*          sinT   = (float*)carve(2048ull * 64 * 4);

  hipLaunchKernelGGL(k_cvt3, dim3(2048), dim3(256), 0, stream,
                     x, x_bf, 2048 * 2048 / 4,
                     qkv_w, w1_bf, 6144 * 2048 / 4,
                     proj_w, w2_bf, 2048 * 2048 / 4,
                     cosT, sinT, h_dim, w_dim);
  hipLaunchKernelGGL(k_gemmQKV, dim3(512), dim3(256), 0, stream,
                     x_bf, w1_bf, qkv_b, qkvb, 2048, 6144, 2048);
  hipLaunchKernelGGL(k_post, dim3(8704), dim3(256), 0, stream,
                     qkvb, q_nw, k_nw, cosT, sinT, q_bf, k_bf, vt2_bf);
  hipLaunchKernelGGL(k_fattn, dim3(512), dim3(256), 0, stream,
                     q_bf, k_bf, vt2_bf, on_bf, lseb);
  hipLaunchKernelGGL(k_merge, dim3(2048), dim3(256), 0, stream, on_bf, lseb, att_bf);
  hipLaunchKernelGGL(k_gemmProj, dim3(16, 32), dim3(256), 0, stream,
                     att_bf, w2_bf, proj_b, out, 2048, 2048, 2048);
}